// Round 1
// baseline (86.078 us; speedup 1.0000x reference)
//
#include <hip/hip_runtime.h>
#include <math.h>

#define BB 8
#define NN 256
#define XHIN 9
#define XHHID 64
#define POSHID 192

// ---------------------------------------------------------------------------
// Kernel A: per-batch masked mean removal + xh embedding (out[...,0:64]).
// One block per batch, one thread per node. Centered x stored SoA in ws.
// ---------------------------------------------------------------------------
__global__ __launch_bounds__(256) void emb_center_kernel(
    const float* __restrict__ xh, const float* __restrict__ mask,
    const float* __restrict__ Wxh, const float* __restrict__ bxh,
    float* __restrict__ out, float* __restrict__ ws_xc, float* __restrict__ ws_cnt)
{
  const int b = blockIdx.x;
  const int n = threadIdx.x;

  const float* p = xh + (b * NN + n) * XHIN;
  float v[XHIN];
  #pragma unroll
  for (int k = 0; k < XHIN; ++k) v[k] = p[k];
  const float m = mask[b * NN + n];

  // masked sums of x[0..2] and mask count, wave-64 shuffle reduce
  float a0 = v[0] * m, a1 = v[1] * m, a2 = v[2] * m, a3 = m;
  #pragma unroll
  for (int off = 32; off > 0; off >>= 1) {
    a0 += __shfl_down(a0, off, 64);
    a1 += __shfl_down(a1, off, 64);
    a2 += __shfl_down(a2, off, 64);
    a3 += __shfl_down(a3, off, 64);
  }
  __shared__ float red[4][4];
  __shared__ float Wl[XHIN * XHHID];
  __shared__ float bl[XHHID];
  const int lane = n & 63, wv = n >> 6;
  if (lane == 0) { red[wv][0] = a0; red[wv][1] = a1; red[wv][2] = a2; red[wv][3] = a3; }
  for (int idx = n; idx < XHIN * XHHID; idx += 256) Wl[idx] = Wxh[idx];
  if (n < XHHID) bl[n] = bxh[n];
  __syncthreads();

  const float s0 = red[0][0] + red[1][0] + red[2][0] + red[3][0];
  const float s1 = red[0][1] + red[1][1] + red[2][1] + red[3][1];
  const float s2 = red[0][2] + red[1][2] + red[2][2] + red[3][2];
  const float cnt = red[0][3] + red[1][3] + red[2][3] + red[3][3];
  const float inv = 1.0f / cnt;

  v[0] = (v[0] - s0 * inv) * m;
  v[1] = (v[1] - s1 * inv) * m;
  v[2] = (v[2] - s2 * inv) * m;

  // SoA layout for coalesced reads in pe_kernel: ws_xc[(b*3+c)*NN + n]
  ws_xc[(b * 3 + 0) * NN + n] = v[0];
  ws_xc[(b * 3 + 1) * NN + n] = v[1];
  ws_xc[(b * 3 + 2) * NN + n] = v[2];
  if (n == 0) ws_cnt[b] = cnt;

  float* o = out + (size_t)(b * NN + n) * 256;
  for (int oo = 0; oo < XHHID; ++oo) {
    float acc = bl[oo];
    #pragma unroll
    for (int k = 0; k < XHIN; ++k) acc = fmaf(v[k], Wl[k * XHHID + oo], acc);
    o[oo] = acc * m;
  }
}

// ---------------------------------------------------------------------------
// Kernel B: one block per (b,i) row. Sum-then-matmul reassociation:
//   out_pe[i] = mi * (S_i @ W_pos)/cnt + mi*256/cnt * b_pos,
//   S_i[f]    = sum_j mask_j * sin(2*pi*d_ij*freq_f)   (and cos in [64,128))
// sin via HW v_sin (revolutions) after explicit v_fract range reduction
// (d*freq reaches ~900 revolutions — outside HW domain without fract).
// ---------------------------------------------------------------------------
__global__ __launch_bounds__(256) void pe_kernel(
    const float* __restrict__ ws_xc, const float* __restrict__ ws_cnt,
    const float* __restrict__ mask, const float* __restrict__ Wp,
    const float* __restrict__ bp, float* __restrict__ out)
{
  const int blk = blockIdx.x;
  const int b = blk >> 8;
  const int i = blk & 255;
  const int tid = threadIdx.x;

  __shared__ float dist_s[NN];
  __shared__ float mask_s[NN];
  __shared__ float part[4][128];
  __shared__ float Ssc[128];

  // phase 1: distances for all j (coalesced SoA reads)
  const float* xcb = ws_xc + b * 3 * NN;
  const float xi0 = xcb[0 * NN + i];
  const float xi1 = xcb[1 * NN + i];
  const float xi2 = xcb[2 * NN + i];
  {
    const int j = tid;
    const float dx = xi0 - xcb[0 * NN + j];
    const float dy = xi1 - xcb[1 * NN + j];
    const float dz = xi2 - xcb[2 * NN + j];
    const float sq = dx * dx + dy * dy + dz * dz;
    dist_s[j] = sqrtf(sq + 1e-12f);
    mask_s[j] = mask[b * NN + j];
  }
  __syncthreads();

  // phase 2: thread (jg,f): accumulate sin/cos for freq f over 64 j's
  const int f = tid & 63, jg = tid >> 6;
  // freq = 100^(f/64) = exp2(f * log2(100)/64); double once per thread for accuracy
  const float freq = (float)exp2((double)f * 0.10381025296523007);
  float ss = 0.f, cc = 0.f;
  const int j0 = jg * 64;
  #pragma unroll 16
  for (int u = 0; u < 64; ++u) {
    const float d = dist_s[j0 + u];   // LDS broadcast within wave
    const float mj = mask_s[j0 + u];
    const float r = d * freq;         // revolutions
    const float rv = r - floorf(r);   // v_fract range reduction
    ss = fmaf(__builtin_amdgcn_sinf(rv), mj, ss);
    cc = fmaf(__builtin_amdgcn_cosf(rv), mj, cc);
  }
  part[jg][f] = ss;
  part[jg][64 + f] = cc;
  __syncthreads();

  const float mi = mask[b * NN + i];
  const float cnt = ws_cnt[b];
  if (tid < 128) {
    const float s = part[0][tid] + part[1][tid] + part[2][tid] + part[3][tid];
    Ssc[tid] = s * (mi / cnt);
  }
  __syncthreads();

  // phase 3: 192 outputs, 128-MAC dot each; Wp reads coalesced, Ssc broadcast
  if (tid < POSHID) {
    float acc = 0.f;
    #pragma unroll 8
    for (int k = 0; k < 128; ++k) acc = fmaf(Ssc[k], Wp[k * POSHID + tid], acc);
    acc += bp[tid] * (mi * 256.0f / cnt);
    out[(size_t)(b * NN + i) * 256 + 64 + tid] = acc;
  }
}

extern "C" void kernel_launch(void* const* d_in, const int* in_sizes, int n_in,
                              void* d_out, int out_size, void* d_ws, size_t ws_size,
                              hipStream_t stream) {
  // setup_inputs order: t, xh, node_mask, edge_mask, W_xh, b_xh, W_pos, b_pos
  const float* xh   = (const float*)d_in[1];
  const float* mask = (const float*)d_in[2];
  const float* Wxh  = (const float*)d_in[4];
  const float* bxh  = (const float*)d_in[5];
  const float* Wp   = (const float*)d_in[6];
  const float* bp   = (const float*)d_in[7];
  float* out = (float*)d_out;

  float* ws_xc  = (float*)d_ws;           // B*3*N floats (SoA centered x)
  float* ws_cnt = ws_xc + BB * 3 * NN;    // B floats (mask counts)

  emb_center_kernel<<<BB, 256, 0, stream>>>(xh, mask, Wxh, bxh, out, ws_xc, ws_cnt);
  pe_kernel<<<BB * NN, 256, 0, stream>>>(ws_xc, ws_cnt, mask, Wp, bp, out);
}

// Round 2
// 83.134 us; speedup vs baseline: 1.0354x; 1.0354x over previous
//
#include <hip/hip_runtime.h>
#include <math.h>

#define BB 8
#define NN 256
#define XHIN 9
#define XHHID 64
#define POSHID 192

// ---------------------------------------------------------------------------
// Kernel A: per-batch masked mean removal only. One block per batch.
// Writes centered x SoA (ws_xc[(b*3+c)*NN+n]) and mask count (ws_cnt[b]).
// ---------------------------------------------------------------------------
__global__ __launch_bounds__(256) void mean_kernel(
    const float* __restrict__ xh, const float* __restrict__ mask,
    float* __restrict__ ws_xc, float* __restrict__ ws_cnt)
{
  const int b = blockIdx.x;
  const int n = threadIdx.x;

  const float* p = xh + (b * NN + n) * XHIN;
  const float x0 = p[0], x1 = p[1], x2 = p[2];
  const float m = mask[b * NN + n];

  float a0 = x0 * m, a1 = x1 * m, a2 = x2 * m, a3 = m;
  #pragma unroll
  for (int off = 32; off > 0; off >>= 1) {
    a0 += __shfl_down(a0, off, 64);
    a1 += __shfl_down(a1, off, 64);
    a2 += __shfl_down(a2, off, 64);
    a3 += __shfl_down(a3, off, 64);
  }
  __shared__ float red[4][4];
  const int lane = n & 63, wv = n >> 6;
  if (lane == 0) { red[wv][0] = a0; red[wv][1] = a1; red[wv][2] = a2; red[wv][3] = a3; }
  __syncthreads();

  const float s0 = red[0][0] + red[1][0] + red[2][0] + red[3][0];
  const float s1 = red[0][1] + red[1][1] + red[2][1] + red[3][1];
  const float s2 = red[0][2] + red[1][2] + red[2][2] + red[3][2];
  const float cnt = red[0][3] + red[1][3] + red[2][3] + red[3][3];
  const float inv = 1.0f / cnt;

  ws_xc[(b * 3 + 0) * NN + n] = (x0 - s0 * inv) * m;
  ws_xc[(b * 3 + 1) * NN + n] = (x1 - s1 * inv) * m;
  ws_xc[(b * 3 + 2) * NN + n] = (x2 - s2 * inv) * m;
  if (n == 0) ws_cnt[b] = cnt;
}

// ---------------------------------------------------------------------------
// Kernel B: one block per (b,i) row. Does BOTH output halves:
//   out[...,  0: 64] = ([xc_i, h_i] @ W_xh + b_xh) * mi      (threads 192..255)
//   out[..., 64:256] = mi*(S_i @ W_pos)/cnt + mi*256/cnt*b_pos (threads 0..191)
// where S_i[f] = sum_j mask_j * sin(2*pi*d_ij*freq_f) (cos in [64,128)).
// LDS-issue optimizations: (dist,mask) packed float2 -> ds_read_b64 broadcast;
// Ssc read as float4 -> ds_read_b128 broadcast.
// ---------------------------------------------------------------------------
__global__ __launch_bounds__(256) void pe_kernel(
    const float* __restrict__ ws_xc, const float* __restrict__ ws_cnt,
    const float* __restrict__ mask, const float* __restrict__ xh,
    const float* __restrict__ Wxh, const float* __restrict__ bxh,
    const float* __restrict__ Wp, const float* __restrict__ bp,
    float* __restrict__ out)
{
  const int blk = blockIdx.x;
  const int b = blk >> 8;
  const int i = blk & 255;
  const int tid = threadIdx.x;

  __shared__ float2 dm_s[NN];                    // (dist, mask_j)
  __shared__ float part[4][128];
  __shared__ __align__(16) float Ssc[128];
  __shared__ float ins_s[XHIN];                  // [xc_i(3), h_i(6)]

  // phase 1: distances for all j (coalesced SoA reads)
  const float* xcb = ws_xc + b * 3 * NN;
  const float xi0 = xcb[0 * NN + i];
  const float xi1 = xcb[1 * NN + i];
  const float xi2 = xcb[2 * NN + i];
  {
    const int j = tid;
    const float dx = xi0 - xcb[0 * NN + j];
    const float dy = xi1 - xcb[1 * NN + j];
    const float dz = xi2 - xcb[2 * NN + j];
    const float sq = fmaf(dx, dx, fmaf(dy, dy, dz * dz));
    dm_s[j] = make_float2(sqrtf(sq + 1e-12f), mask[b * NN + j]);
  }
  if (tid < XHIN)
    ins_s[tid] = (tid < 3) ? xcb[tid * NN + i] : xh[(b * NN + i) * XHIN + tid];
  __syncthreads();

  // phase 2: thread (jg,f): accumulate sin/cos for freq f over 64 j's
  const int f = tid & 63, jg = tid >> 6;
  // freq = 100^(f/64) = exp2(f * log2(100)/64)
  const float freq = __builtin_exp2f((float)f * 0.10381025296523007f);
  float ss = 0.f, cc = 0.f;
  const float2* dmp = dm_s + jg * 64;
  #pragma unroll 16
  for (int u = 0; u < 64; ++u) {
    const float2 dm = dmp[u];                    // one b64 broadcast / iter
    const float rv = __builtin_amdgcn_fractf(dm.x * freq);  // revolutions
    ss = fmaf(__builtin_amdgcn_sinf(rv), dm.y, ss);
    cc = fmaf(__builtin_amdgcn_cosf(rv), dm.y, cc);
  }
  part[jg][f] = ss;
  part[jg][64 + f] = cc;
  __syncthreads();

  const float cnt = ws_cnt[b];
  const float mi = dm_s[i].y;                    // mask_i, already staged
  if (tid < 128)
    Ssc[tid] = (part[0][tid] + part[1][tid] + part[2][tid] + part[3][tid]) * (mi / cnt);
  __syncthreads();

  if (tid < POSHID) {
    // phase 3a: 192 pe outputs, 128-MAC dot; Ssc via b128 broadcasts
    const float4* S4 = (const float4*)Ssc;
    float acc = bp[tid] * (mi * 256.0f / cnt);
    #pragma unroll 8
    for (int k4 = 0; k4 < 32; ++k4) {
      const float4 s = S4[k4];
      const float* w = Wp + (k4 * 4) * POSHID + tid;
      acc = fmaf(s.x, w[0 * POSHID], acc);
      acc = fmaf(s.y, w[1 * POSHID], acc);
      acc = fmaf(s.z, w[2 * POSHID], acc);
      acc = fmaf(s.w, w[3 * POSHID], acc);
    }
    out[(size_t)(b * NN + i) * 256 + 64 + tid] = acc;
  } else {
    // phase 3b (concurrent): 64 xh-embedding outputs for this node
    const int oo = tid - POSHID;                 // 0..63
    float acc = bxh[oo];
    #pragma unroll
    for (int k = 0; k < XHIN; ++k)
      acc = fmaf(ins_s[k], Wxh[k * XHHID + oo], acc);
    out[(size_t)(b * NN + i) * 256 + oo] = acc * mi;
  }
}

extern "C" void kernel_launch(void* const* d_in, const int* in_sizes, int n_in,
                              void* d_out, int out_size, void* d_ws, size_t ws_size,
                              hipStream_t stream) {
  // setup_inputs order: t, xh, node_mask, edge_mask, W_xh, b_xh, W_pos, b_pos
  const float* xh   = (const float*)d_in[1];
  const float* mask = (const float*)d_in[2];
  const float* Wxh  = (const float*)d_in[4];
  const float* bxh  = (const float*)d_in[5];
  const float* Wp   = (const float*)d_in[6];
  const float* bp   = (const float*)d_in[7];
  float* out = (float*)d_out;

  float* ws_xc  = (float*)d_ws;           // B*3*N floats (SoA centered x)
  float* ws_cnt = ws_xc + BB * 3 * NN;    // B floats (mask counts)

  mean_kernel<<<BB, 256, 0, stream>>>(xh, mask, ws_xc, ws_cnt);
  pe_kernel<<<BB * NN, 256, 0, stream>>>(ws_xc, ws_cnt, mask, xh, Wxh, bxh, Wp, bp, out);
}